// Round 2
// baseline (196.944 us; speedup 1.0000x reference)
//
#include <hip/hip_runtime.h>

// B=32, N=1024, D=256. out = softmax((x Wq^T + bq)(x Wk^T + bk)^T) (x Wv^T + bv)
// All matmuls in fp16 MFMA (fp32 accumulate): score-noise std ~0.011 vs bf16's 0.126.
#define NN 1024
#define DD 256

typedef __attribute__((ext_vector_type(8))) _Float16 f16x8;  // 8 fp16 = 4 VGPRs
typedef __attribute__((ext_vector_type(4))) float f32x4;

union H8 { f16x8 v; _Float16 s[8]; };

// ---------------- kernel 1: weights fp32 -> fp16 (concat [Wq;Wk;Wv] as [768][256]) ---
__global__ void wconv_kernel(const float* __restrict__ Wq, const float* __restrict__ Wk,
                             const float* __restrict__ Wv, _Float16* __restrict__ whf) {
  int idx = blockIdx.x * 256 + threadIdx.x;      // < 768*256
  int e = idx >> 8, d = idx & 255;
  const float* W = (e < 256) ? Wq : (e < 512 ? Wk : Wv);
  whf[idx] = (_Float16)W[(e & 255) * 256 + d];
}

// ---------------- kernel 2: QKV projection -------------------------------------------
// grid 512 blocks, 256 thr. Block = 64 m-rows x all 768 e-cols.
// q,k stored row-major fp16 [32768][256]; v stored transposed fp16 [b][d][m%N].
__global__ __launch_bounds__(256, 2) void proj_kernel(
    const float* __restrict__ traj,
    const float* __restrict__ bq, const float* __restrict__ bk, const float* __restrict__ bv,
    const _Float16* __restrict__ whf,
    _Float16* __restrict__ qhf, _Float16* __restrict__ khf,
    _Float16* __restrict__ vthf)
{
  __shared__ _Float16 Ws[32 * 264];   // 16896 B, pad 264 -> 2-way-free frag reads
  __shared__ _Float16 Cs[64 * 88];    // 11264 B epilogue staging (stride 88: aligned+2-way)

  const int t = threadIdx.x;
  const int lane = t & 63, wave = t >> 6;
  const int col16 = lane & 15, quad = lane >> 4;
  const int mbase = blockIdx.x * 64;

  // A fragments straight from global fp32 (A[m=lane&15][k=quad*8+j]), row read once.
  f16x8 aq[8];
  {
    const float* ap = traj + (size_t)(mbase + wave * 16 + col16) * DD;
    for (int kk = 0; kk < 8; ++kk) {
      float4 u0 = *(const float4*)(ap + kk * 32 + quad * 8);
      float4 u1 = *(const float4*)(ap + kk * 32 + quad * 8 + 4);
      H8 xx;
      xx.s[0] = (_Float16)u0.x; xx.s[1] = (_Float16)u0.y;
      xx.s[2] = (_Float16)u0.z; xx.s[3] = (_Float16)u0.w;
      xx.s[4] = (_Float16)u1.x; xx.s[5] = (_Float16)u1.y;
      xx.s[6] = (_Float16)u1.z; xx.s[7] = (_Float16)u1.w;
      aq[kk] = xx.v;
    }
  }

  f32x4 acc[4];
  const f32x4 zero = {0.f, 0.f, 0.f, 0.f};

  for (int et = 0; et < 12; ++et) {
    for (int h = 0; h < 2; ++h) {
      __syncthreads();                       // prev Ws reads / prev Cs reads done
      {                                      // stage 32 e-rows of W (fp16), 8 thr/row
        int row = t >> 3;
        const _Float16* wsrc = whf + (size_t)(et * 64 + h * 32 + row) * 256;
        for (int i = 0; i < 4; ++i) {
          int c = (t & 7) + i * 8;           // 0..31 chunks of 16B
          *(int4*)&Ws[row * 264 + c * 8] = *(const int4*)(wsrc + c * 8);
        }
      }
      __syncthreads();
      if (h == 0) { acc[0] = zero; acc[1] = zero; acc[2] = zero; acc[3] = zero; }
      for (int kk = 0; kk < 8; ++kk)
        for (int n2 = 0; n2 < 2; ++n2) {
          f16x8 bw = *(const f16x8*)&Ws[(n2 * 16 + col16) * 264 + kk * 32 + quad * 8];
          acc[h * 2 + n2] =
              __builtin_amdgcn_mfma_f32_16x16x32_f16(aq[kk], bw, acc[h * 2 + n2], 0, 0, 0);
        }
    }
    // epilogue for this 64-col tile: bias, fp16, coalesced store via LDS
    int ebase = et * 64;
    int sel = ebase >> 8;                    // 0=q 1=k 2=v
    const float* bias = (sel == 0) ? bq : (sel == 1 ? bk : bv);
    for (int nt = 0; nt < 4; ++nt) {
      float bvl = bias[(ebase & 255) + nt * 16 + col16];
      acc[nt][0] += bvl; acc[nt][1] += bvl; acc[nt][2] += bvl; acc[nt][3] += bvl;
    }
    if (sel < 2) {
      for (int nt = 0; nt < 4; ++nt)
        for (int r = 0; r < 4; ++r)          // C layout: col=lane&15, row=quad*4+r
          Cs[(wave * 16 + quad * 4 + r) * 88 + nt * 16 + col16] = (_Float16)acc[nt][r];
      __syncthreads();
      _Float16* dst = (sel == 0) ? qhf : khf;
      int row = t >> 2;
      int colg = ebase & 255;
      for (int i = 0; i < 2; ++i) {
        int c = (t & 3) + i * 4;             // 8 chunks of 16B per 64-col row
        *(int4*)(dst + (size_t)(mbase + row) * 256 + colg + c * 8) =
            *(const int4*)&Cs[row * 88 + c * 8];
      }
    } else {
      for (int nt = 0; nt < 4; ++nt)
        for (int r = 0; r < 4; ++r)          // transposed staging: [e_local][m_local]
          Cs[(nt * 16 + col16) * 88 + (wave * 16 + quad * 4 + r)] = (_Float16)acc[nt][r];
      __syncthreads();
      int trow = t >> 2;                     // e-local 0..63
      int dglob = (ebase - 512) + trow;
      int bb = mbase >> 10;
      int mloc = mbase & 1023;
      for (int i = 0; i < 2; ++i) {
        int c = (t & 3) + i * 4;
        *(int4*)(vthf + ((size_t)bb * 256 + dglob) * NN + mloc + c * 8) =
            *(const int4*)&Cs[trow * 88 + c * 8];
      }
    }
  }
}

// ---------------- kernel 3: flash attention ------------------------------------------
// grid (16,32): x = q-tile (64 rows), y = batch. 4 waves, wave owns 16 q-rows.
__global__ __launch_bounds__(256, 2) void attn_kernel(
    const _Float16* __restrict__ qhf, const _Float16* __restrict__ khf,
    const _Float16* __restrict__ vthf, float* __restrict__ out)
{
  __shared__ _Float16 Ks[64 * 264];    // 33792 B
  __shared__ _Float16 VTs[128 * 72];   // 18432 B (half of d at a time)
  __shared__ _Float16 Ps[64 * 88];     // 11264 B   -> total 63488 B < 64 KiB

  const int t = threadIdx.x;
  const int lane = t & 63, wave = t >> 6;
  const int col16 = lane & 15, quad = lane >> 4;
  const int qt = blockIdx.x, b = blockIdx.y;
  const int qrow0 = b * NN + qt * 64;

  // Q fragments direct from global fp16 (coalesced 64B/row)
  f16x8 aq[8];
  {
    const _Float16* qp = qhf + (size_t)(qrow0 + wave * 16 + col16) * DD;
    for (int kk = 0; kk < 8; ++kk)
      aq[kk] = *(const f16x8*)(qp + kk * 32 + quad * 8);
  }

  float m_i[4], l_i[4], alpha[4];
  f32x4 O[16];
  const f32x4 zero = {0.f, 0.f, 0.f, 0.f};
  for (int r = 0; r < 4; ++r) { m_i[r] = -3.0e38f; l_i[r] = 0.f; }
  for (int dt = 0; dt < 16; ++dt) O[dt] = zero;

  const _Float16* kbase = khf + (size_t)(b * NN) * DD;
  const _Float16* vbase = vthf + (size_t)b * DD * NN;

  for (int kt = 0; kt < 16; ++kt) {
    __syncthreads();                         // prev iter's PV reads done
    {                                        // stage K tile 64x256 fp16, 4 thr/row
      int row = t >> 2;
      const _Float16* ks = kbase + (size_t)(kt * 64 + row) * DD;
      for (int i = 0; i < 8; ++i) {
        int c = (t & 3) + i * 4;
        *(int4*)&Ks[row * 264 + c * 8] = *(const int4*)(ks + c * 8);
      }
    }
    for (int g = 0; g < 2; ++g) {            // stage VT d-rows 0..127
      int dr = g * 64 + (t >> 2);
      const _Float16* vs = vbase + (size_t)dr * NN + kt * 64;
      for (int i = 0; i < 2; ++i) {
        int c = (t & 3) + i * 4;
        *(int4*)&VTs[dr * 72 + c * 8] = *(const int4*)(vs + c * 8);
      }
    }
    __syncthreads();

    // S = Q K^T  (64 keys)
    f32x4 S[4]; S[0] = zero; S[1] = zero; S[2] = zero; S[3] = zero;
    for (int kk = 0; kk < 8; ++kk)
      for (int nt = 0; nt < 4; ++nt) {
        f16x8 bk_ = *(const f16x8*)&Ks[(nt * 16 + col16) * 264 + kk * 32 + quad * 8];
        S[nt] = __builtin_amdgcn_mfma_f32_16x16x32_f16(aq[kk], bk_, S[nt], 0, 0, 0);
      }

    // online softmax — rows quad*4+r are private to this wave's 16-lane quads
    for (int r = 0; r < 4; ++r) {
      float vmax = fmaxf(fmaxf(S[0][r], S[1][r]), fmaxf(S[2][r], S[3][r]));
      vmax = fmaxf(vmax, __shfl_xor(vmax, 1));
      vmax = fmaxf(vmax, __shfl_xor(vmax, 2));
      vmax = fmaxf(vmax, __shfl_xor(vmax, 4));
      vmax = fmaxf(vmax, __shfl_xor(vmax, 8));
      float nm = fmaxf(m_i[r], vmax);
      alpha[r] = __expf(m_i[r] - nm);
      float rs = 0.f;
      for (int nt = 0; nt < 4; ++nt) {
        float pv = __expf(S[nt][r] - nm);
        S[nt][r] = pv;
        rs += pv;
      }
      rs += __shfl_xor(rs, 1);
      rs += __shfl_xor(rs, 2);
      rs += __shfl_xor(rs, 4);
      rs += __shfl_xor(rs, 8);
      l_i[r] = l_i[r] * alpha[r] + rs;
      m_i[r] = nm;
    }
    for (int dt = 0; dt < 16; ++dt)
      for (int r = 0; r < 4; ++r) O[dt][r] *= alpha[r];

    // P -> LDS (C layout -> A layout round trip; rows are wave-private, no barrier)
    for (int nt = 0; nt < 4; ++nt)
      for (int r = 0; r < 4; ++r)
        Ps[(wave * 16 + quad * 4 + r) * 88 + nt * 16 + col16] = (_Float16)S[nt][r];
    f16x8 ap[2];
    for (int k2 = 0; k2 < 2; ++k2)
      ap[k2] = *(const f16x8*)&Ps[(wave * 16 + col16) * 88 + k2 * 32 + quad * 8];

    // O += P V, d 0..127
    for (int dt = 0; dt < 8; ++dt)
      for (int k2 = 0; k2 < 2; ++k2) {
        f16x8 bv_ = *(const f16x8*)&VTs[(dt * 16 + col16) * 72 + k2 * 32 + quad * 8];
        O[dt] = __builtin_amdgcn_mfma_f32_16x16x32_f16(ap[k2], bv_, O[dt], 0, 0, 0);
      }
    __syncthreads();
    for (int g = 0; g < 2; ++g) {            // stage VT d-rows 128..255
      int dr = g * 64 + (t >> 2);
      const _Float16* vs = vbase + (size_t)(128 + dr) * NN + kt * 64;
      for (int i = 0; i < 2; ++i) {
        int c = (t & 3) + i * 4;
        *(int4*)&VTs[dr * 72 + c * 8] = *(const int4*)(vs + c * 8);
      }
    }
    __syncthreads();
    // O += P V, d 128..255
    for (int dt = 0; dt < 8; ++dt)
      for (int k2 = 0; k2 < 2; ++k2) {
        f16x8 bv_ = *(const f16x8*)&VTs[(dt * 16 + col16) * 72 + k2 * 32 + quad * 8];
        O[8 + dt] = __builtin_amdgcn_mfma_f32_16x16x32_f16(ap[k2], bv_, O[8 + dt], 0, 0, 0);
      }
  }

  // epilogue: O /= l, fp32 store (lanes 0..15 contiguous 64B per instr)
  for (int r = 0; r < 4; ++r) {
    float inv = 1.0f / l_i[r];
    float* orow = out + (size_t)(qrow0 + wave * 16 + quad * 4 + r) * DD;
    for (int dt = 0; dt < 16; ++dt)
      orow[dt * 16 + col16] = O[dt][r] * inv;
  }
}

// ---------------- launch -------------------------------------------------------------
extern "C" void kernel_launch(void* const* d_in, const int* in_sizes, int n_in,
                              void* d_out, int out_size, void* d_ws, size_t ws_size,
                              hipStream_t stream) {
  const float* traj = (const float*)d_in[0];
  const float* Wq   = (const float*)d_in[1];
  const float* bq   = (const float*)d_in[2];
  const float* Wk   = (const float*)d_in[3];
  const float* bk   = (const float*)d_in[4];
  const float* Wv   = (const float*)d_in[5];
  const float* bv   = (const float*)d_in[6];

  // workspace layout (fp16): q[32768][256] | k[32768][256] | vT[32][256][1024] | w[768][256]
  _Float16* qhf  = (_Float16*)d_ws;
  _Float16* khf  = qhf  + (size_t)32768 * 256;
  _Float16* vthf = khf  + (size_t)32768 * 256;
  _Float16* whf  = vthf + (size_t)32768 * 256;   // ~48.4 MB total

  wconv_kernel<<<768, 256, 0, stream>>>(Wq, Wk, Wv, whf);
  proj_kernel<<<512, 256, 0, stream>>>(traj, bq, bk, bv, whf, qhf, khf, vthf);
  attn_kernel<<<dim3(16, 32), 256, 0, stream>>>(qhf, khf, vthf, (float*)d_out);
}